// Round 6
// baseline (1152.959 us; speedup 1.0000x reference)
//
#include <hip/hip_runtime.h>
#include <hip/hip_bf16.h>

// ComplexAttentivePooling: B=16,S=8192,D=512,H=8,K=V=64
// R6: fix R5's missing-columns bug (8 waves x 64 cols = 512 of 1024 cols; heads 4-7
// read garbage past partn[]). Restore R4's ch 2-pass loop around the barrier-free
// VGPR-W K-loop. ch loop fully unrolled (rule #20: no runtime-indexed reg arrays).
//  - W in per-wave VGPRs, 1-deep pipeline, no K-loop barriers
//  - x prefetched to VGPRs at last W-phase of pass 1 (in-order vmcnt)
//  - DPP row_ror epilogue reduce (VALU pipe; keeps DS pipe for A-frags)
//  - y/ssum accumulated across 8 tiles, atomics once per block

#define CB 16
#define CS 8192
#define CD 512
#define CH 8
#define CK 64
#define NCOL 128
#define TM 64
#define NT 8            // tiles per block; grid 256 = 1 block/CU
#define EPSV 1e-12f

typedef __attribute__((ext_vector_type(8))) unsigned short us8;
typedef __attribute__((ext_vector_type(8))) __bf16 bf16x8;
typedef __attribute__((ext_vector_type(4))) float f32x4;

__device__ __forceinline__ unsigned short f2bf(float f) {
  __hip_bfloat16 h = __float2bfloat16(f);
  return *reinterpret_cast<unsigned short*>(&h);
}
__device__ __forceinline__ float bf2f(unsigned short u) {
  unsigned int x = ((unsigned int)u) << 16;
  return __uint_as_float(x);
}
__device__ __forceinline__ bf16x8 as_bf(us8 u) { return __builtin_bit_cast(bf16x8, u); }

// sum across each 16-lane DPP row via row_ror 8/4/2/1 (pure VALU, no LDS)
__device__ __forceinline__ float ror_add16(float v) {
  int x;
  x = __builtin_amdgcn_update_dpp(0, __float_as_int(v), 0x128, 0xf, 0xf, false);
  v += __int_as_float(x);
  x = __builtin_amdgcn_update_dpp(0, __float_as_int(v), 0x124, 0xf, 0xf, false);
  v += __int_as_float(x);
  x = __builtin_amdgcn_update_dpp(0, __float_as_int(v), 0x122, 0xf, 0xf, false);
  v += __int_as_float(x);
  x = __builtin_amdgcn_update_dpp(0, __float_as_int(v), 0x121, 0xf, 0xf, false);
  v += __int_as_float(x);
  return v;
}

// ---------------- prep: tiled transpose Wq -> wbt [1024 cols][512 k] bf16 ----------------
__global__ void cap_prep(const float* __restrict__ Wq_r, const float* __restrict__ Wq_i,
                         unsigned short* __restrict__ wbt) {
  __shared__ float tile[64][65];
  int blk = blockIdx.x, t = threadIdx.x;
  int ri = blk >> 6, h = (blk >> 3) & 7, dt = blk & 7;
  const float* src = (ri ? Wq_i : Wq_r) + (size_t)h * CD * CK + (size_t)dt * 64 * CK;
  #pragma unroll
  for (int p = 0; p < 16; ++p) {
    int idx = p * 256 + t;
    int d = idx >> 6, c = idx & 63;
    tile[d][c] = src[(size_t)d * CK + c];
  }
  __syncthreads();
  int l = t & 63;
  #pragma unroll
  for (int p = 0; p < 16; ++p) {
    int c = p * 4 + (t >> 6);
    wbt[((size_t)(h * NCOL + ri * 64 + c)) * CD + dt * 64 + l] = f2bf(tile[l][c]);
  }
}

// ---------------- keys: wvec = [kr,-ki]/||key||, bqc = [bq_r,bq_i] ----------------
__global__ void cap_keys(const float* __restrict__ key_real, const float* __restrict__ key_imag,
                         const float* __restrict__ bq_r, const float* __restrict__ bq_i,
                         float* __restrict__ wvec, float* __restrict__ bqc) {
  int h = blockIdx.x, t = threadIdx.x;
  __shared__ float kn;
  if (t < 64) {
    float a = key_real[h * CK + t], b2 = key_imag[h * CK + t];
    float s = a * a + b2 * b2;
    #pragma unroll
    for (int off = 1; off < 64; off <<= 1) s += __shfl_xor(s, off);
    if (t == 0) kn = sqrtf(fmaxf(s, EPSV));
  }
  __syncthreads();
  float v = (t < CK) ? key_real[h * CK + t] : -key_imag[h * CK + (t - CK)];
  wvec[h * NCOL + t] = v / kn;
  bqc[h * NCOL + t] = (t < CK) ? bq_r[h * CK + t] : bq_i[h * CK + (t - CK)];
}

// ---------------- main fused kernel: grid 256 (16 b x 16 s-groups), 512 thr ----------------
#define XL_BYTES 65536
#define SMEM_BYTES (XL_BYTES + 3 * 512 * 4)

__global__ __launch_bounds__(512, 2) void cap_main(
    const float* __restrict__ x, const int* __restrict__ mask,
    const unsigned short* __restrict__ wbt, const float* __restrict__ wvec,
    const float* __restrict__ bqc, float* __restrict__ yws, float* __restrict__ ssum) {
  extern __shared__ char smem[];
  char* Xl = smem;                                  // [64 rows][1024 B] swizzled bf16
  float* scoresA = (float*)(smem + XL_BYTES);       // [8][64]
  float* partn = scoresA + 512;                     // [8][64]
  float* partm = partn + 512;                       // [8][64]

  const int tid = threadIdx.x;
  const int w = tid >> 6, l = tid & 63;
  const int lr = l & 15, q = l >> 4;
  const int b = blockIdx.x >> 4;
  const int s_base = (blockIdx.x & 15) * (NT * TM);
  const float* xbase = x + ((size_t)b * CS + s_base) * CD;
  const us8* wbt8 = (const us8*)wbt;
  const int hw = w >> 1, chalf = w & 1;

  float yacc[CH], ssacc[CH];
  #pragma unroll
  for (int h = 0; h < CH; ++h) { yacc[h] = 0.f; ssacc[h] = 0.f; }

  float4 xp[16];

  // ---- prologue: stage tile 0
  #pragma unroll
  for (int i = 0; i < 8; ++i) {
    int id = i * 512 + tid;
    int row = id >> 6, cc = id & 63;
    const float* src = xbase + row * CD + cc * 8;
    xp[i * 2] = *(const float4*)(src);
    xp[i * 2 + 1] = *(const float4*)(src + 4);
  }
  #pragma unroll
  for (int i = 0; i < 8; ++i) {
    int id = i * 512 + tid;
    int row = id >> 6, cc = id & 63;
    float4 f0 = xp[i * 2], f1 = xp[i * 2 + 1];
    us8 v;
    v[0] = f2bf(f0.x); v[1] = f2bf(f0.y); v[2] = f2bf(f0.z); v[3] = f2bf(f0.w);
    v[4] = f2bf(f1.x); v[5] = f2bf(f1.y); v[6] = f2bf(f1.z); v[7] = f2bf(f1.w);
    *(us8*)(Xl + row * 1024 + ((cc * 16) ^ ((row & 7) << 4))) = v;
  }
  __syncthreads();

  #pragma unroll 1
  for (int t = 0; t < NT; ++t) {
    // ---- two passes: ch=0 -> heads 0..3 (cols 0..511), ch=1 -> heads 4..7.
    // Fully unrolled so every register-array index is compile-time (rule #20).
    #pragma unroll
    for (int ch = 0; ch < 2; ++ch) {
      const int hh = ch * 4 + hw;
      // byte-level: col = hh*128 + chalf*64 + n*16 + lr; us8 off = col*64 + q
      const us8* wB = wbt8 + (size_t)hh * 8192 + chalf * 4096 + lr * 64 + q;

      f32x4 acc[4][4];
      #pragma unroll
      for (int m = 0; m < 4; ++m)
        #pragma unroll
        for (int n = 0; n < 4; ++n) acc[m][n] = (f32x4){0.f, 0.f, 0.f, 0.f};

      us8 wbuf[2][4];
      #pragma unroll
      for (int n = 0; n < 4; ++n) wbuf[0][n] = wB[n * 1024];

      #pragma unroll
      for (int kc = 0; kc < 16; ++kc) {
        if (kc < 15) {
          #pragma unroll
          for (int n = 0; n < 4; ++n)
            wbuf[(kc + 1) & 1][n] = wB[n * 1024 + (kc + 1) * 4];
        }
        if (ch == 1 && kc == 15 && t < NT - 1) {
          // x-prefetch AFTER all W issues of this tile (in-order vmcnt)
          const float* xnext = xbase + (size_t)(t + 1) * TM * CD;
          #pragma unroll
          for (int i = 0; i < 8; ++i) {
            int id = i * 512 + tid;
            int row = id >> 6, cc = id & 63;
            const float* src = xnext + row * CD + cc * 8;
            xp[i * 2] = *(const float4*)(src);
            xp[i * 2 + 1] = *(const float4*)(src + 4);
          }
        }
        bf16x8 a[4];
        #pragma unroll
        for (int m = 0; m < 4; ++m) {
          int row = m * 16 + lr;
          a[m] = as_bf(*(const us8*)(Xl + row * 1024 +
                                     ((kc * 64 + q * 16) ^ ((row & 7) << 4))));
        }
        #pragma unroll
        for (int m = 0; m < 4; ++m)
          #pragma unroll
          for (int n = 0; n < 4; ++n)
            acc[m][n] = __builtin_amdgcn_mfma_f32_16x16x32_bf16(
                a[m], as_bf(wbuf[kc & 1][n]), acc[m][n], 0, 0, 0);
      }

      // ---- epilogue pass ch: n2/nm per token row, DPP reduce over 16 lr-lanes
      float wv_[4], bq_[4];
      #pragma unroll
      for (int n = 0; n < 4; ++n) {
        int c = hh * NCOL + chalf * 64 + n * 16 + lr;
        wv_[n] = wvec[c];
        bq_[n] = bqc[c];
      }
      float n2[4][4], nm[4][4];
      #pragma unroll
      for (int m = 0; m < 4; ++m)
        #pragma unroll
        for (int r = 0; r < 4; ++r) { n2[m][r] = 0.f; nm[m][r] = 0.f; }
      #pragma unroll
      for (int n = 0; n < 4; ++n)
        #pragma unroll
        for (int m = 0; m < 4; ++m)
          #pragma unroll
          for (int r = 0; r < 4; ++r) {
            float qv = acc[m][n][r] + bq_[n];  // C: col=lane&15, row=(lane>>4)*4+r
            n2[m][r] += qv * qv;
            nm[m][r] += qv * wv_[n];
          }
      #pragma unroll
      for (int m = 0; m < 4; ++m)
        #pragma unroll
        for (int r = 0; r < 4; ++r) {
          n2[m][r] = ror_add16(n2[m][r]);
          nm[m][r] = ror_add16(nm[m][r]);
        }
      if (lr == 0) {
        #pragma unroll
        for (int m = 0; m < 4; ++m)
          #pragma unroll
          for (int r = 0; r < 4; ++r) {
            int row = m * 16 + q * 4 + r;
            partn[w * 64 + row] = n2[m][r];
            partm[w * 64 + row] = nm[m][r];
          }
      }
      __syncthreads();
      if (tid < 64) {
        float mk = (mask[(size_t)b * CS + s_base + t * TM + tid] != 0) ? 1.0f : 0.0f;
        #pragma unroll
        for (int hl = 0; hl < 4; ++hl) {
          float nn = partn[(2 * hl) * 64 + tid] + partn[(2 * hl + 1) * 64 + tid];
          float mm = partm[(2 * hl) * 64 + tid] + partm[(2 * hl + 1) * 64 + tid];
          float sc = mm / sqrtf(fmaxf(nn, EPSV)) * mk;
          scoresA[(ch * 4 + hl) * 64 + tid] = sc;
          ssacc[ch * 4 + hl] += sc;
        }
      }
      __syncthreads();
    }

    // ---- y-pass: yacc[h] += sum_row score[h][row] * x_bf16[row][d=tid]
    {
      int d = tid;
      float sreg[CH];
      #pragma unroll
      for (int h = 0; h < CH; ++h) sreg[h] = scoresA[h * 64 + l];
      #pragma unroll 4
      for (int row = 0; row < TM; ++row) {
        float xv = bf2f(*(const unsigned short*)(
            Xl + row * 1024 + ((d * 2) ^ ((row & 7) << 4))));
        #pragma unroll
        for (int h = 0; h < CH; ++h) {
          float sc = __uint_as_float(
              __builtin_amdgcn_readlane(__float_as_uint(sreg[h]), row));
          yacc[h] += sc * xv;
        }
      }
    }
    __syncthreads();

    if (t < NT - 1) {
      // cvt + write prefetched tile (compiler emits the vmcnt wait for xp here)
      #pragma unroll
      for (int i = 0; i < 8; ++i) {
        int id = i * 512 + tid;
        int row = id >> 6, cc = id & 63;
        float4 f0 = xp[i * 2], f1 = xp[i * 2 + 1];
        us8 v;
        v[0] = f2bf(f0.x); v[1] = f2bf(f0.y); v[2] = f2bf(f0.z); v[3] = f2bf(f0.w);
        v[4] = f2bf(f1.x); v[5] = f2bf(f1.y); v[6] = f2bf(f1.z); v[7] = f2bf(f1.w);
        *(us8*)(Xl + row * 1024 + ((cc * 16) ^ ((row & 7) << 4))) = v;
      }
      __syncthreads();
    }
  }

  // ---- block-end: commit y and ssum
  #pragma unroll
  for (int h = 0; h < CH; ++h)
    atomicAdd(&yws[((size_t)b * CH + h) * CD + tid], yacc[h]);
  if (tid < 64) {
    #pragma unroll
    for (int h = 0; h < CH; ++h) {
      float s = ssacc[h];
      #pragma unroll
      for (int off = 1; off < 64; off <<= 1) s += __shfl_xor(s, off);
      if (l == 0) atomicAdd(&ssum[b * CH + h], s);
    }
  }
}

// ---------------- finish: pooled = y@Wv + ssum*bv ; out = pooled@Wf + bf ----------------
// grid 16 (one per b), 512 threads
__global__ void cap_finish(const float* __restrict__ yws, const float* __restrict__ ssum,
                           const float* __restrict__ Wv, const float* __restrict__ bv,
                           const float* __restrict__ Wf, const float* __restrict__ bfv,
                           float* __restrict__ out) {
  __shared__ float yl[CH * CD];
  __shared__ float pl[512];
  __shared__ float ss[CH];
  int b = blockIdx.x, t = threadIdx.x;
  #pragma unroll
  for (int i = 0; i < 8; ++i) yl[i * 512 + t] = yws[(size_t)b * CH * CD + i * 512 + t];
  if (t < CH) ss[t] = ssum[b * CH + t];
  __syncthreads();
  {
    int h = t >> 6, v = t & 63;
    float acc = ss[h] * bv[h * CK + v];
    const float* yrow = yl + h * CD;
    const float* wcol = Wv + (size_t)h * CD * CK + v;
    #pragma unroll 8
    for (int d = 0; d < CD; ++d) acc += yrow[d] * wcol[(size_t)d * CK];
    pl[t] = acc;
  }
  __syncthreads();
  {
    float o = bfv[t];
    #pragma unroll 8
    for (int j = 0; j < 512; ++j) o += pl[j] * Wf[(size_t)j * CD + t];
    out[(size_t)b * CD + t] = o;
  }
}

extern "C" void kernel_launch(void* const* d_in, const int* in_sizes, int n_in,
                              void* d_out, int out_size, void* d_ws, size_t ws_size,
                              hipStream_t stream) {
  const float* x = (const float*)d_in[0];
  const int* mask = (const int*)d_in[1];   // bool staged as int32
  const float* Wq_r = (const float*)d_in[2];
  const float* bq_r = (const float*)d_in[3];
  const float* Wq_i = (const float*)d_in[4];
  const float* bq_i = (const float*)d_in[5];
  const float* Wv = (const float*)d_in[6];
  const float* bv = (const float*)d_in[7];
  const float* key_real = (const float*)d_in[8];
  const float* key_imag = (const float*)d_in[9];
  const float* Wf = (const float*)d_in[10];
  const float* bfv = (const float*)d_in[11];
  float* out = (float*)d_out;

  char* ws = (char*)d_ws;
  unsigned short* wbt = (unsigned short*)ws;                         // 1 MB
  float* wvec = (float*)(ws + (1 << 20));                            // 4 KB
  float* bqc  = (float*)(ws + (1 << 20) + 4096);                     // 4 KB
  float* yws  = (float*)(ws + (1 << 20) + 8192);                     // 256 KB
  float* ssum = (float*)(ws + (1 << 20) + 8192 + CB * CH * CD * 4);  // 512 B

  hipMemsetAsync(yws, 0, CB * CH * CD * 4 + CB * CH * 4, stream);
  cap_prep<<<dim3(128), dim3(256), 0, stream>>>(Wq_r, Wq_i, wbt);
  cap_keys<<<dim3(8), dim3(128), 0, stream>>>(key_real, key_imag, bq_r, bq_i, wvec, bqc);
  hipFuncSetAttribute((const void*)cap_main,
                      hipFuncAttributeMaxDynamicSharedMemorySize, SMEM_BYTES);
  cap_main<<<dim3(CB * 16), dim3(512), SMEM_BYTES, stream>>>(
      x, mask, wbt, wvec, bqc, yws, ssum);
  cap_finish<<<dim3(CB), dim3(512), 0, stream>>>(yws, ssum, Wv, bv, Wf, bfv, out);
}